// Round 2
// baseline (384.659 us; speedup 1.0000x reference)
//
#include <hip/hip_runtime.h>
#include <hip/hip_bf16.h>
#include <cstdint>
#include <cstddef>

// ---------------------------------------------------------------------------
// AttentionLayer: out = gamma * softmax((x@g) @ (input_h@f)^T) @ input_h + x
// B=4, W=64 (N=4096), C=C2=512, D=64.  I/O tensors are FLOAT32.
// Q,K,V,weights bf16 for MFMA; softmax + O-accum fp32.
// Fixed-max softmax: p = exp(min(s,80)-20)  (legit |s| <~ 9; clamp is
// NaN-proofing only).  Denominator accumulated per-thread, reduced once.
// ALL MFMAs 16x16x32_bf16 (HW-verified maps):
//   A: [m=lane&15][k=(lane>>4)*8+j]   B: [n=lane&15][k=(lane>>4)*8+j]
//   C/D: col=lane&15, row=(lane>>4)*4+reg
//
// R6 (post-mortem of R5): channel-split duplicated phase A (exp/f2bf/P LDS)
// x4 -> VALUBusy 53%, bank-conflict cycles x4, dur 140->191.  REVERTED.
// Instead: query-split.  32-row q tiles -> grid 512 (2 blocks/CU), 8 waves;
// phase A = 8 S-tiles of 16x16 = one per wave (NO redundant softmax work
// anywhere); wave keeps a 64-chan slice in phase B (acc[2][4]).
// Plus: single barrier per key-tile.  Plds double-buffered like Klds;
// iteration = [stage K(kb+1); A(kb); barrier; B(kb)].  Window between
// barriers touches {B(kb-1):Pbuf[kb-1&1], A(kb):Pbuf[kb&1]w,Klds[kb&1]r,
// stage:Klds[kb+1&1]w} -- all disjoint.  2 blocks/CU fill each drain.
//
// ws layout (20.1MB, non-overlapping): fT 64K @0 | gT 64K @64K | Qg 2M @128K |
// Kf 2M @2.125M | Vt 16M @4.125M.
// ---------------------------------------------------------------------------

#define NPOS 4096
#define CCH  512
#define DQK  64
#define LSTR 72   // LDS row stride (elements): 144B rows, 16B-aligned frags

typedef __attribute__((ext_vector_type(8)))  short s8v;   // 8 bf16 (4 VGPR)
typedef __attribute__((ext_vector_type(4)))  short s4v;   // 4 bf16
typedef __attribute__((ext_vector_type(4)))  float f4v;

__device__ __forceinline__ float bf2f(unsigned short u) {
    unsigned int x = ((unsigned int)u) << 16;
    return __builtin_bit_cast(float, x);
}
__device__ __forceinline__ unsigned short f2bf(float f) {
    unsigned int u = __builtin_bit_cast(unsigned int, f);
    u += 0x7fffu + ((u >> 16) & 1u);   // round-to-nearest-even
    return (unsigned short)(u >> 16);
}

// --------------------------- weight transpose ------------------------------
// f,g: [512,64] fp32 -> fT,gT: [64,512] bf16.
__global__ __launch_bounds__(256) void wt_kernel(
    const float* __restrict__ f, const float* __restrict__ g,
    unsigned short* __restrict__ fT, unsigned short* __restrict__ gT)
{
    int gid = blockIdx.x * 256 + threadIdx.x;   // grid 64 -> 16384 threads
    for (int e = 0; e < 4; ++e) {
        int i = e * 16384 + gid;                // 0..65535
        int which = i >> 15;
        int j = i & 32767;
        int d = j >> 9, k = j & 511;
        const float* s = which ? g : f;
        unsigned short* dst = which ? gT : fT;
        dst[j] = f2bf(s[k * 64 + d]);           // dst[d][k] = src[k][d]
    }
}

// ----------------------------- V transpose ---------------------------------
// input_h [b][n][c] fp32 -> Vt [b][c][n] bf16.  64x64 tiles through LDS
// (stride 65 breaks bank conflicts on the column gathers).
__global__ __launch_bounds__(256) void vt_kernel(
    const float* __restrict__ ih, unsigned short* __restrict__ Vt)
{
    __shared__ unsigned short T[64 * 65];
    const int tid = threadIdx.x;
    const int bidx = blockIdx.x;
    const int bb = bidx >> 9;      // batch
    const int rem = bidx & 511;
    const int ct = rem >> 6;       // c tile 0..7
    const int nt = rem & 63;       // n tile 0..63

    for (int p = 0; p < 4; ++p) {
        int idx = p * 256 + tid;           // 0..1023
        int r = idx >> 4, gg = idx & 15;   // row 0..63, float4 group 0..15
        f4v v = *(const f4v*)(ih + ((size_t)bb * NPOS + nt * 64 + r) * CCH + ct * 64 + gg * 4);
        for (int j = 0; j < 4; ++j) T[r * 65 + gg * 4 + j] = f2bf(v[j]);
    }
    __syncthreads();
    for (int p = 0; p < 2; ++p) {
        int idx = p * 256 + tid;
        int c = idx >> 3, ng = idx & 7;
        unsigned short tmp[8];
        for (int j = 0; j < 8; ++j) tmp[j] = T[(ng * 8 + j) * 65 + c];
        *(s8v*)(Vt + ((size_t)bb * CCH + ct * 64 + c) * NPOS + nt * 64 + ng * 8) = *(const s8v*)tmp;
    }
}

// ------------------------------ projections --------------------------------
// which=0: Q = x @ g   (16384 rows, K=512, 64 cols).  which=1: K = ih @ f.
__global__ __launch_bounds__(256) void proj_kernel(
    const float* __restrict__ x,  const float* __restrict__ ih,
    const unsigned short* __restrict__ gT, const unsigned short* __restrict__ fT,
    unsigned short* __restrict__ Qg, unsigned short* __restrict__ Kf)
{
    __shared__ __align__(16) short Alds[128 * LSTR];
    __shared__ __align__(16) short Wlds[64 * LSTR];
    const int tid = threadIdx.x;
    const int wave = tid >> 6, lane = tid & 63;
    const int n15 = lane & 15, quad = lane >> 4;
    const int which = blockIdx.x >> 7;
    const int rb = (blockIdx.x & 127) * 128;
    const float* src = which ? ih : x;
    const unsigned short* wT  = which ? fT : gT;
    unsigned short* dst = which ? Kf : Qg;

    f4v acc[2][4];   // [row-tile][col-tile]
    for (int i = 0; i < 2; ++i)
        for (int j = 0; j < 4; ++j)
            acc[i][j] = f4v{0.f, 0.f, 0.f, 0.f};

    for (int kc = 0; kc < 8; ++kc) {
        // A tile: 128 rows x 64 k, fp32 -> bf16
        for (int p = 0; p < 8; ++p) {
            int idx = p * 256 + tid;           // 0..2047
            int r = idx >> 4, gg = idx & 15;   // row 0..127, float4 group
            f4v v = *(const f4v*)(src + (size_t)(rb + r) * CCH + kc * 64 + gg * 4);
            s4v tv;
            for (int j = 0; j < 4; ++j) tv[j] = (short)f2bf(v[j]);
            *(s4v*)&Alds[r * LSTR + gg * 4] = tv;
        }
        // W tile: 64 cols(d) x 64 k, already bf16
        for (int p = 0; p < 2; ++p) {
            int idx = p * 256 + tid;
            int c = idx >> 3, gg = idx & 7;
            *(s8v*)&Wlds[c * LSTR + gg * 8] =
                *(const s8v*)(wT + (size_t)c * CCH + kc * 64 + gg * 8);
        }
        __syncthreads();
        for (int kk = 0; kk < 2; ++kk) {       // two K=32 chunks of the 64-tile
            s8v af0 = *(const s8v*)&Alds[(wave * 32 +      n15) * LSTR + kk * 32 + quad * 8];
            s8v af1 = *(const s8v*)&Alds[(wave * 32 + 16 + n15) * LSTR + kk * 32 + quad * 8];
            for (int ct = 0; ct < 4; ++ct) {
                s8v bf = *(const s8v*)&Wlds[(ct * 16 + n15) * LSTR + kk * 32 + quad * 8];
                acc[0][ct] = __builtin_amdgcn_mfma_f32_16x16x32_bf16(af0, bf, acc[0][ct], 0, 0, 0);
                acc[1][ct] = __builtin_amdgcn_mfma_f32_16x16x32_bf16(af1, bf, acc[1][ct], 0, 0, 0);
            }
        }
        __syncthreads();
    }
    for (int rt = 0; rt < 2; ++rt)
        for (int ct = 0; ct < 4; ++ct)
            for (int r = 0; r < 4; ++r) {
                int row = wave * 32 + rt * 16 + quad * 4 + r;
                int col = ct * 16 + n15;
                dst[(size_t)(rb + row) * DQK + col] = f2bf(acc[rt][ct][r]);
            }
}

// ------------------------------ flash attention ----------------------------
// One block per (batch, 32-row query tile). 8 waves; wave w owns channel
// slice [w*64, w*64+64) as 4 16-wide tiles.  Phase A: wave w computes S-tile
// (ti=w>>2, mi=w&3) -- exactly one 16x16 tile per wave, no redundancy.
// Single barrier per key-tile (Klds AND Plds double-buffered).
__global__ __launch_bounds__(512, 4) void flash_kernel(
    const unsigned short* __restrict__ Qg,
    const unsigned short* __restrict__ Kf,
    const unsigned short* __restrict__ Vt,
    const float* __restrict__ xin,
    const float* __restrict__ gptr,
    float* __restrict__ out)
{
    __shared__ __align__(16) short Klds[2 * 64 * LSTR];  // double-buffered K
    __shared__ __align__(16) short Plds[2 * 32 * LSTR];  // double-buffered P
    __shared__ float l_s[32];

    const int tid = threadIdx.x;
    const int wave = tid >> 6;
    const int lane = tid & 63;
    const int n15 = lane & 15, quad = lane >> 4;
    const int bid = blockIdx.x;
    // XCD swizzle: batch b -> XCD pair so per-XCD Vt working set = 4MB (L2-hot).
    // grid 512: bid&7 = xcd, b = xcd>>1; qt = (xcd&1) + ((bid>>3)<<1), 0..127.
    const int xcd = bid & 7;
    const int b = xcd >> 1;
    const int qt = (xcd & 1) + ((bid >> 3) << 1);
    const int qbase = qt * 32;

    const float SOFT_M = 20.0f;
    float lpart = 0.0f;

    f4v acc[2][4];   // [query-tile(2x16)][channel-tile(4x16)]
    for (int i = 0; i < 2; ++i)
        for (int j = 0; j < 4; ++j)
            acc[i][j] = f4v{0.f, 0.f, 0.f, 0.f};

    // Phase-A tile assignment: wave w -> S rows ti*16.., key cols mi*16..
    const int ti = wave >> 2;
    const int mi = wave & 3;
    s8v qf[2];
    {
        const unsigned short* qp =
            Qg + ((size_t)b * NPOS + qbase + ti * 16 + n15) * DQK + quad * 8;
        qf[0] = *(const s8v*)(qp);
        qf[1] = *(const s8v*)(qp + 32);
    }

    const int cb = wave * 64;   // phase-B channel base for this wave
    // Per-lane V row pointers: channel = cb + ct*16 + n15, key offset quad*8.
    const unsigned short* Vb = Vt + (size_t)b * CCH * NPOS;
    const unsigned short* vp[4];
    for (int ct = 0; ct < 4; ++ct)
        vp[ct] = Vb + (size_t)(cb + ct * 16 + n15) * NPOS + quad * 8;

    // K staging: one 16B chunk per thread per tile (64 rows x 8 groups)
    const int kr = tid >> 3, kg = tid & 7;
    const unsigned short* kbase_p = Kf + ((size_t)b * NPOS + kr) * DQK + kg * 8;

    // Prologue: stage K(0), prefetch K(1) into kreg, one barrier.
    s8v kreg = *(const s8v*)(kbase_p);
    *(s8v*)&Klds[kr * LSTR + kg * 8] = kreg;
    kreg = *(const s8v*)(kbase_p + (size_t)64 * DQK);
    __syncthreads();

    for (int kb = 0; kb < NPOS / 64; ++kb) {
        const int m0 = kb * 64;
        // V B-frags (global, L2-hot): vf[ct][kk][j] = V[m0+kk*32+quad*8+j][ch]
        s8v vf[4][2];
        for (int ct = 0; ct < 4; ++ct) {
            vf[ct][0] = *(const s8v*)(vp[ct] + m0);
            vf[ct][1] = *(const s8v*)(vp[ct] + m0 + 32);
        }
        // stage K(kb+1) from kreg; prefetch K(kb+2)
        if (kb + 1 < NPOS / 64) {
            *(s8v*)&Klds[((kb + 1) & 1) * 64 * LSTR + kr * LSTR + kg * 8] = kreg;
            if (kb + 2 < NPOS / 64)
                kreg = *(const s8v*)(kbase_p + (size_t)(m0 + 128) * DQK);
        }

        // ---- phase A: one 16x16 S tile per wave -> P -> Pbuf[kb&1] ----
        {
            const short* Kb = &Klds[(kb & 1) * 64 * LSTR];
            short* Pb = &Plds[(kb & 1) * 32 * LSTR];
            f4v s4 = f4v{0.f, 0.f, 0.f, 0.f};
            for (int ks = 0; ks < 2; ++ks) {
                s8v kf = *(const s8v*)&Kb[(mi * 16 + n15) * LSTR + ks * 32 + quad * 8];
                s4 = __builtin_amdgcn_mfma_f32_16x16x32_bf16(qf[ks], kf, s4, 0, 0, 0);
            }
            const int col = mi * 16 + n15;
            const int row0 = ti * 16 + quad * 4;
            for (int r = 0; r < 4; ++r)
                Pb[(row0 + r) * LSTR + col] =
                    (short)f2bf(__expf(fminf(s4[r], 80.0f) - SOFT_M));
        }
        __syncthreads();   // single barrier: Pbuf[kb&1] ready; Klds[(kb+1)&1] staged

        // ---- phase B: denominator partials + O += P @ V ----
        {
            const short* Pb = &Plds[(kb & 1) * 32 * LSTR];
            {   // 512 threads cover 32 rows x 16 4-wide groups exactly
                const int r = tid >> 4, g4 = tid & 15;
                s4v p4 = *(const s4v*)&Pb[r * LSTR + g4 * 4];
                float ls = 0.f;
                for (int e = 0; e < 4; ++e) ls += bf2f((unsigned short)p4[e]);
                lpart += ls;
            }
            for (int kk = 0; kk < 2; ++kk) {
                s8v af[2];
                for (int q4 = 0; q4 < 2; ++q4)
                    af[q4] = *(const s8v*)&Pb[(q4 * 16 + n15) * LSTR + kk * 32 + quad * 8];
                for (int q4 = 0; q4 < 2; ++q4)
                    for (int ct = 0; ct < 4; ++ct)
                        acc[q4][ct] = __builtin_amdgcn_mfma_f32_16x16x32_bf16(
                            af[q4], vf[ct][kk], acc[q4][ct], 0, 0, 0);
            }
        }
        // next iter: A(kb+1) writes Pbuf[(kb+1)&1] (other buffer), stage writes
        // Klds[(kb+2)&1] after barrier(kb+1) -- no hazard with this B(kb).
    }

    // ---- denominator reduction: 16 threads per row -> l_s[row] ----
    lpart += __shfl_xor(lpart, 1);
    lpart += __shfl_xor(lpart, 2);
    lpart += __shfl_xor(lpart, 4);
    lpart += __shfl_xor(lpart, 8);
    if ((tid & 15) == 0) l_s[tid >> 4] = lpart;
    __syncthreads();

    // ---- epilogue: out = gamma * O / l + x  (fp32 I/O, scalar l reads) ----
    const float gamma = gptr[0];
    for (int q4 = 0; q4 < 2; ++q4) {
        for (int r = 0; r < 4; ++r) {
            const int row = q4 * 16 + quad * 4 + r;
            const float sc = gamma / l_s[row];
            for (int ct = 0; ct < 4; ++ct) {
                const int col = cb + ct * 16 + n15;
                const size_t idx = ((size_t)b * NPOS + qbase + row) * CCH + col;
                out[idx] = acc[q4][ct][r] * sc + xin[idx];
            }
        }
    }
}

// ---------------------------------------------------------------------------
extern "C" void kernel_launch(void* const* d_in, const int* in_sizes, int n_in,
                              void* d_out, int out_size, void* d_ws, size_t ws_size,
                              hipStream_t stream)
{
    const float* x     = (const float*)d_in[0];
    const float* ih    = (const float*)d_in[1];
    const float* f     = (const float*)d_in[2];
    const float* g     = (const float*)d_in[3];
    const float* gamma = (const float*)d_in[4];
    float* out = (float*)d_out;

    char* ws = (char*)d_ws;
    unsigned short* fT = (unsigned short*)(ws + 0);         // 64x512 bf16 (64KB)
    unsigned short* gT = (unsigned short*)(ws + 65536);     // 64x512 bf16 (64KB)
    unsigned short* Qg = (unsigned short*)(ws + 131072);    // 16384x64 bf16 (2MB)
    unsigned short* Kf = (unsigned short*)(ws + 2228224);   // 16384x64 bf16 (2MB)
    unsigned short* Vt = (unsigned short*)(ws + 4325376);   // 4x512x4096 bf16 (16MB)
    // total ws use: 21,102,592 bytes (~20.1MB), non-overlapping.

    wt_kernel<<<64, 256, 0, stream>>>(f, g, fT, gT);
    vt_kernel<<<2048, 256, 0, stream>>>(ih, Vt);
    proj_kernel<<<256, 256, 0, stream>>>(x, ih, gT, fT, Qg, Kf);
    flash_kernel<<<512, 512, 0, stream>>>(Qg, Kf, Vt, x, gamma, out);
}

// Round 3
// 276.560 us; speedup vs baseline: 1.3909x; 1.3909x over previous
//
#include <hip/hip_runtime.h>
#include <hip/hip_bf16.h>
#include <cstdint>
#include <cstddef>

// ---------------------------------------------------------------------------
// AttentionLayer: out = gamma * softmax((x@g) @ (input_h@f)^T) @ input_h + x
// B=4, W=64 (N=4096), C=C2=512, D=64.  I/O tensors are FLOAT32.
// Q,K,V,weights bf16 for MFMA; softmax + O-accum fp32.
// Fixed-max softmax: p = exp(min(s,80)-20)  (legit |s| <~ 9; clamp is
// NaN-proofing only).
// ALL MFMAs 16x16x32_bf16 (HW-verified maps):
//   A: [m=lane&15][k=(lane>>4)*8+j]   B: [n=lane&15][k=(lane>>4)*8+j]
//   C/D: col=lane&15, row=(lane>>4)*4+reg
//
// R7 (post-mortems R5/R6): R5 ch-split duplicated softmax x4 (VALU-bound,
// 191us).  R6 q-split duplicated V L2 traffic x2 + thin windows (253us).
// Both REVERTED.  This round keeps R4's work partition EXACTLY (QBLK=64,
// KVBLK=64, grid 256, V read once per block, softmax 1x) and fixes only the
// OVERLAP: 16 waves (1024 thr) = 4 waves/SIMD (R4 was 2), single barrier
// per window (R6's verified dbuf scheme: K and P both double-buffered,
// stage K(i+1) + phaseA(i) | barrier | phaseB(i); all cross-wave buffer
// parities disjoint), denominator accumulated in-register during phase A
// (removes the per-iter P re-read + decode), reduced once at the end.
// Phase A: wave w -> S-tile (ti=w>>2, mi=w&3), 1 tile/wave, no redundancy.
// Phase B: wave w -> 32-chan slice, acc[4][2], vf[2][2].
//
// ws layout (20.1MB, non-overlapping): fT 64K @0 | gT 64K @64K | Qg 2M @128K |
// Kf 2M @2.125M | Vt 16M @4.125M.
// ---------------------------------------------------------------------------

#define NPOS 4096
#define CCH  512
#define DQK  64
#define LSTR 72   // LDS row stride (elements): 144B rows, 16B-aligned frags

typedef __attribute__((ext_vector_type(8)))  short s8v;   // 8 bf16 (4 VGPR)
typedef __attribute__((ext_vector_type(4)))  short s4v;   // 4 bf16
typedef __attribute__((ext_vector_type(4)))  float f4v;

__device__ __forceinline__ float bf2f(unsigned short u) {
    unsigned int x = ((unsigned int)u) << 16;
    return __builtin_bit_cast(float, x);
}
__device__ __forceinline__ unsigned short f2bf(float f) {
    unsigned int u = __builtin_bit_cast(unsigned int, f);
    u += 0x7fffu + ((u >> 16) & 1u);   // round-to-nearest-even
    return (unsigned short)(u >> 16);
}

// --------------------------- weight transpose ------------------------------
// f,g: [512,64] fp32 -> fT,gT: [64,512] bf16.
__global__ __launch_bounds__(256) void wt_kernel(
    const float* __restrict__ f, const float* __restrict__ g,
    unsigned short* __restrict__ fT, unsigned short* __restrict__ gT)
{
    int gid = blockIdx.x * 256 + threadIdx.x;   // grid 64 -> 16384 threads
    for (int e = 0; e < 4; ++e) {
        int i = e * 16384 + gid;                // 0..65535
        int which = i >> 15;
        int j = i & 32767;
        int d = j >> 9, k = j & 511;
        const float* s = which ? g : f;
        unsigned short* dst = which ? gT : fT;
        dst[j] = f2bf(s[k * 64 + d]);           // dst[d][k] = src[k][d]
    }
}

// ----------------------------- V transpose ---------------------------------
// input_h [b][n][c] fp32 -> Vt [b][c][n] bf16.  64x64 tiles through LDS
// (stride 65 breaks bank conflicts on the column gathers).
__global__ __launch_bounds__(256) void vt_kernel(
    const float* __restrict__ ih, unsigned short* __restrict__ Vt)
{
    __shared__ unsigned short T[64 * 65];
    const int tid = threadIdx.x;
    const int bidx = blockIdx.x;
    const int bb = bidx >> 9;      // batch
    const int rem = bidx & 511;
    const int ct = rem >> 6;       // c tile 0..7
    const int nt = rem & 63;       // n tile 0..63

    for (int p = 0; p < 4; ++p) {
        int idx = p * 256 + tid;           // 0..1023
        int r = idx >> 4, gg = idx & 15;   // row 0..63, float4 group 0..15
        f4v v = *(const f4v*)(ih + ((size_t)bb * NPOS + nt * 64 + r) * CCH + ct * 64 + gg * 4);
        for (int j = 0; j < 4; ++j) T[r * 65 + gg * 4 + j] = f2bf(v[j]);
    }
    __syncthreads();
    for (int p = 0; p < 2; ++p) {
        int idx = p * 256 + tid;
        int c = idx >> 3, ng = idx & 7;
        unsigned short tmp[8];
        for (int j = 0; j < 8; ++j) tmp[j] = T[(ng * 8 + j) * 65 + c];
        *(s8v*)(Vt + ((size_t)bb * CCH + ct * 64 + c) * NPOS + nt * 64 + ng * 8) = *(const s8v*)tmp;
    }
}

// ------------------------------ projections --------------------------------
// which=0: Q = x @ g   (16384 rows, K=512, 64 cols).  which=1: K = ih @ f.
__global__ __launch_bounds__(256) void proj_kernel(
    const float* __restrict__ x,  const float* __restrict__ ih,
    const unsigned short* __restrict__ gT, const unsigned short* __restrict__ fT,
    unsigned short* __restrict__ Qg, unsigned short* __restrict__ Kf)
{
    __shared__ __align__(16) short Alds[128 * LSTR];
    __shared__ __align__(16) short Wlds[64 * LSTR];
    const int tid = threadIdx.x;
    const int wave = tid >> 6, lane = tid & 63;
    const int n15 = lane & 15, quad = lane >> 4;
    const int which = blockIdx.x >> 7;
    const int rb = (blockIdx.x & 127) * 128;
    const float* src = which ? ih : x;
    const unsigned short* wT  = which ? fT : gT;
    unsigned short* dst = which ? Kf : Qg;

    f4v acc[2][4];   // [row-tile][col-tile]
    for (int i = 0; i < 2; ++i)
        for (int j = 0; j < 4; ++j)
            acc[i][j] = f4v{0.f, 0.f, 0.f, 0.f};

    for (int kc = 0; kc < 8; ++kc) {
        // A tile: 128 rows x 64 k, fp32 -> bf16
        for (int p = 0; p < 8; ++p) {
            int idx = p * 256 + tid;           // 0..2047
            int r = idx >> 4, gg = idx & 15;   // row 0..127, float4 group
            f4v v = *(const f4v*)(src + (size_t)(rb + r) * CCH + kc * 64 + gg * 4);
            s4v tv;
            for (int j = 0; j < 4; ++j) tv[j] = (short)f2bf(v[j]);
            *(s4v*)&Alds[r * LSTR + gg * 4] = tv;
        }
        // W tile: 64 cols(d) x 64 k, already bf16
        for (int p = 0; p < 2; ++p) {
            int idx = p * 256 + tid;
            int c = idx >> 3, gg = idx & 7;
            *(s8v*)&Wlds[c * LSTR + gg * 8] =
                *(const s8v*)(wT + (size_t)c * CCH + kc * 64 + gg * 8);
        }
        __syncthreads();
        for (int kk = 0; kk < 2; ++kk) {       // two K=32 chunks of the 64-tile
            s8v af0 = *(const s8v*)&Alds[(wave * 32 +      n15) * LSTR + kk * 32 + quad * 8];
            s8v af1 = *(const s8v*)&Alds[(wave * 32 + 16 + n15) * LSTR + kk * 32 + quad * 8];
            for (int ct = 0; ct < 4; ++ct) {
                s8v bf = *(const s8v*)&Wlds[(ct * 16 + n15) * LSTR + kk * 32 + quad * 8];
                acc[0][ct] = __builtin_amdgcn_mfma_f32_16x16x32_bf16(af0, bf, acc[0][ct], 0, 0, 0);
                acc[1][ct] = __builtin_amdgcn_mfma_f32_16x16x32_bf16(af1, bf, acc[1][ct], 0, 0, 0);
            }
        }
        __syncthreads();
    }
    for (int rt = 0; rt < 2; ++rt)
        for (int ct = 0; ct < 4; ++ct)
            for (int r = 0; r < 4; ++r) {
                int row = wave * 32 + rt * 16 + quad * 4 + r;
                int col = ct * 16 + n15;
                dst[(size_t)(rb + row) * DQK + col] = f2bf(acc[rt][ct][r]);
            }
}

// ------------------------------ flash attention ----------------------------
// One block per (batch, 64-row query tile), 1024 threads = 16 waves
// (4 waves/SIMD).  Phase A: wave w computes S-tile (ti=w>>2, mi=w&3) -- one
// 16x16 tile per wave, no redundancy; denominator partials accumulated in
// registers here.  Phase B: wave w owns 32-chan slice [w*32, w*32+32).
// Single barrier per key-tile (Klds AND Plds double-buffered).
__global__ __launch_bounds__(1024) void flash_kernel(
    const unsigned short* __restrict__ Qg,
    const unsigned short* __restrict__ Kf,
    const unsigned short* __restrict__ Vt,
    const float* __restrict__ xin,
    const float* __restrict__ gptr,
    float* __restrict__ out)
{
    __shared__ __align__(16) short Klds[2 * 64 * LSTR];  // double-buffered K
    __shared__ __align__(16) short Plds[2 * 64 * LSTR];  // double-buffered P
    __shared__ float l_part[4][64];                      // per-mi row partials
    __shared__ float l_s[64];

    const int tid = threadIdx.x;
    const int wave = tid >> 6;          // 0..15
    const int lane = tid & 63;
    const int n15 = lane & 15, quad = lane >> 4;
    const int bid = blockIdx.x;
    // XCD swizzle: batch b -> XCD pair so per-XCD Vt working set = 4MB (L2-hot).
    const int xcd = bid & 7;
    const int b = xcd >> 1;
    const int qt = (xcd & 1) + ((bid >> 3) << 1);
    const int qbase = qt * 64;

    const float SOFT_M = 20.0f;

    f4v acc[4][2];   // [query-tile(4x16)][channel-tile(2x16)]
    for (int i = 0; i < 4; ++i)
        for (int j = 0; j < 2; ++j)
            acc[i][j] = f4v{0.f, 0.f, 0.f, 0.f};
    f4v lsum = f4v{0.f, 0.f, 0.f, 0.f};   // denom partials, rows ti*16+quad*4+r

    // Phase-A tile assignment: wave w -> S rows ti*16.., key cols mi*16..
    const int ti = wave >> 2;
    const int mi = wave & 3;
    s8v qf[2];
    {
        const unsigned short* qp =
            Qg + ((size_t)b * NPOS + qbase + ti * 16 + n15) * DQK + quad * 8;
        qf[0] = *(const s8v*)(qp);
        qf[1] = *(const s8v*)(qp + 32);
    }

    const int cb = wave * 32;   // phase-B channel base for this wave
    // Per-lane V row pointers: channel = cb + ct*16 + n15, key offset quad*8.
    const unsigned short* vp0 =
        Vt + ((size_t)b * CCH + cb + n15) * NPOS + quad * 8;
    const unsigned short* vp1 = vp0 + (size_t)16 * NPOS;

    // K staging: waves 0..7 stage (64 rows x 8 16B-groups = 512 threads)
    const int kr = tid >> 3, kg = tid & 7;           // valid for tid<512
    const unsigned short* kbase_p = Kf + ((size_t)b * NPOS + kr) * DQK + kg * 8;
    s8v kreg;
    if (tid < 512) {
        kreg = *(const s8v*)(kbase_p);
        *(s8v*)&Klds[kr * LSTR + kg * 8] = kreg;          // stage K(0)
        kreg = *(const s8v*)(kbase_p + (size_t)64 * DQK); // prefetch K(1)
    }
    __syncthreads();

    for (int kb = 0; kb < NPOS / 64; ++kb) {
        const int m0 = kb * 64;
        // V B-frags (global, L2-hot): vf[ct][kk][j] = V[m0+kk*32+quad*8+j][ch]
        s8v vf[2][2];
        vf[0][0] = *(const s8v*)(vp0 + m0);
        vf[0][1] = *(const s8v*)(vp0 + m0 + 32);
        vf[1][0] = *(const s8v*)(vp1 + m0);
        vf[1][1] = *(const s8v*)(vp1 + m0 + 32);
        // stage K(kb+1) from kreg; prefetch K(kb+2)
        if (tid < 512 && kb + 1 < NPOS / 64) {
            *(s8v*)&Klds[((kb + 1) & 1) * 64 * LSTR + kr * LSTR + kg * 8] = kreg;
            if (kb + 2 < NPOS / 64)
                kreg = *(const s8v*)(kbase_p + (size_t)(m0 + 128) * DQK);
        }

        // ---- phase A: one 16x16 S tile per wave -> P -> Pbuf[kb&1];
        //      denominator partials accumulated in registers ----
        {
            const short* Kb = &Klds[(kb & 1) * 64 * LSTR];
            short* Pb = &Plds[(kb & 1) * 64 * LSTR];
            f4v s4 = f4v{0.f, 0.f, 0.f, 0.f};
            s8v kf0 = *(const s8v*)&Kb[(mi * 16 + n15) * LSTR + quad * 8];
            s8v kf1 = *(const s8v*)&Kb[(mi * 16 + n15) * LSTR + 32 + quad * 8];
            s4 = __builtin_amdgcn_mfma_f32_16x16x32_bf16(qf[0], kf0, s4, 0, 0, 0);
            s4 = __builtin_amdgcn_mfma_f32_16x16x32_bf16(qf[1], kf1, s4, 0, 0, 0);
            const int col = mi * 16 + n15;
            const int row0 = ti * 16 + quad * 4;
            for (int r = 0; r < 4; ++r) {
                unsigned short pb = f2bf(__expf(fminf(s4[r], 80.0f) - SOFT_M));
                Pb[(row0 + r) * LSTR + col] = (short)pb;
                lsum[r] += bf2f(pb);   // sum the ROUNDED value (matches P@1)
            }
        }
        __syncthreads();   // single barrier: Pbuf[kb&1] ready; Klds[(kb+1)&1] staged

        // ---- phase B: O += P @ V for this wave's 32-chan slice ----
        {
            const short* Pb = &Plds[(kb & 1) * 64 * LSTR];
            for (int kk = 0; kk < 2; ++kk) {
                for (int q4 = 0; q4 < 4; ++q4) {
                    s8v af = *(const s8v*)&Pb[(q4 * 16 + n15) * LSTR + kk * 32 + quad * 8];
                    acc[q4][0] = __builtin_amdgcn_mfma_f32_16x16x32_bf16(
                        af, vf[0][kk], acc[q4][0], 0, 0, 0);
                    acc[q4][1] = __builtin_amdgcn_mfma_f32_16x16x32_bf16(
                        af, vf[1][kk], acc[q4][1], 0, 0, 0);
                }
            }
        }
        // next iter: A(kb+1) writes Pbuf[(kb+1)&1]; stage writes Klds[(kb+2)&1]
        // after barrier(kb+1) -- all parities disjoint with this B(kb).
    }

    // ---- denominator: reduce lsum over the 16 n15 lanes (same quad = same
    //      rows), then combine the 4 mi-waves via LDS ----
    for (int d = 1; d < 16; d <<= 1)
        for (int r = 0; r < 4; ++r)
            lsum[r] += __shfl_xor(lsum[r], d);
    if (n15 == 0)
        for (int r = 0; r < 4; ++r)
            l_part[mi][ti * 16 + quad * 4 + r] = lsum[r];
    __syncthreads();
    if (tid < 64)
        l_s[tid] = l_part[0][tid] + l_part[1][tid] + l_part[2][tid] + l_part[3][tid];
    __syncthreads();

    // ---- epilogue: out = gamma * O / l + x  (fp32 I/O, scalar l reads) ----
    const float gamma = gptr[0];
    for (int q4 = 0; q4 < 4; ++q4) {
        for (int r = 0; r < 4; ++r) {
            const int row = q4 * 16 + quad * 4 + r;
            const float sc = gamma / l_s[row];
            const size_t base = ((size_t)b * NPOS + qbase + row) * CCH;
            const int col0 = cb + n15;
            const int col1 = cb + 16 + n15;
            out[base + col0] = acc[q4][0][r] * sc + xin[base + col0];
            out[base + col1] = acc[q4][1][r] * sc + xin[base + col1];
        }
    }
}

// ---------------------------------------------------------------------------
extern "C" void kernel_launch(void* const* d_in, const int* in_sizes, int n_in,
                              void* d_out, int out_size, void* d_ws, size_t ws_size,
                              hipStream_t stream)
{
    const float* x     = (const float*)d_in[0];
    const float* ih    = (const float*)d_in[1];
    const float* f     = (const float*)d_in[2];
    const float* g     = (const float*)d_in[3];
    const float* gamma = (const float*)d_in[4];
    float* out = (float*)d_out;

    char* ws = (char*)d_ws;
    unsigned short* fT = (unsigned short*)(ws + 0);         // 64x512 bf16 (64KB)
    unsigned short* gT = (unsigned short*)(ws + 65536);     // 64x512 bf16 (64KB)
    unsigned short* Qg = (unsigned short*)(ws + 131072);    // 16384x64 bf16 (2MB)
    unsigned short* Kf = (unsigned short*)(ws + 2228224);   // 16384x64 bf16 (2MB)
    unsigned short* Vt = (unsigned short*)(ws + 4325376);   // 4x512x4096 bf16 (16MB)
    // total ws use: 21,102,592 bytes (~20.1MB), non-overlapping.

    wt_kernel<<<64, 256, 0, stream>>>(f, g, fT, gT);
    vt_kernel<<<2048, 256, 0, stream>>>(ih, Vt);
    proj_kernel<<<256, 256, 0, stream>>>(x, ih, gT, fT, Qg, Kf);
    flash_kernel<<<256, 1024, 0, stream>>>(Qg, Kf, Vt, x, gamma, out);
}

// Round 4
// 246.988 us; speedup vs baseline: 1.5574x; 1.1197x over previous
//
#include <hip/hip_runtime.h>
#include <hip/hip_bf16.h>
#include <cstdint>
#include <cstddef>

// ---------------------------------------------------------------------------
// AttentionLayer: out = gamma * softmax((x@g) @ (input_h@f)^T) @ input_h + x
// B=4, W=64 (N=4096), C=C2=512, D=64.  I/O tensors are FLOAT32.
// Q,K,V,weights bf16 for MFMA; softmax + O-accum fp32.
// Fixed-max softmax: p = exp(min(s,80)-20).
// ALL MFMAs 16x16x32_bf16 (HW-verified maps):
//   A: [m=lane&15][k=(lane>>4)*8+j]   B: [n=lane&15][k=(lane>>4)*8+j]
//   C/D: col=lane&15, row=(lane>>4)*4+reg
//
// R8 (post-mortem R7): R4 (8 waves, 2 barriers) and R7 (16 waves, 1 barrier)
// both land at 141us -> bottleneck invariant to waves/barriers/LDS traffic.
// Shared disease: __syncthreads() drains vmcnt(0) every window (compiler
// emits s_waitcnt vmcnt(0) lgkmcnt(0) before s_barrier), exposing the full
// L2/L3 latency of that window's V loads + K prefetch, 64 times.  Fix (T4,
// m218: +38-73%): raw s_barrier preceded by lgkmcnt(0) ONLY (LDS visibility
// kept: all ds_write/ds_read drained; hazard parities of the verified R7
// single-barrier dbuf scheme unchanged), and V prefetched one full window
// ahead (vfc/vfn rotation) so phase-B use is ~1 window after issue.
// proj_kernel gets the same treatment + reg-staged tile prefetch.
//
// ws layout (20.1MB, non-overlapping): fT 64K @0 | gT 64K @64K | Qg 2M @128K |
// Kf 2M @2.125M | Vt 16M @4.125M.
// ---------------------------------------------------------------------------

#define NPOS 4096
#define CCH  512
#define DQK  64
#define LSTR 72   // LDS row stride (elements): 144B rows, 16B-aligned frags

typedef __attribute__((ext_vector_type(8)))  short s8v;   // 8 bf16 (4 VGPR)
typedef __attribute__((ext_vector_type(4)))  short s4v;   // 4 bf16
typedef __attribute__((ext_vector_type(4)))  float f4v;

__device__ __forceinline__ float bf2f(unsigned short u) {
    unsigned int x = ((unsigned int)u) << 16;
    return __builtin_bit_cast(float, x);
}
__device__ __forceinline__ unsigned short f2bf(float f) {
    unsigned int u = __builtin_bit_cast(unsigned int, f);
    u += 0x7fffu + ((u >> 16) & 1u);   // round-to-nearest-even
    return (unsigned short)(u >> 16);
}

// Barrier with LDS visibility but NO vmcnt drain: global loads (register
// destinations, compiler-tracked deps) stay in flight across it.
__device__ __forceinline__ void sync_lds() {
    asm volatile("s_waitcnt lgkmcnt(0)" ::: "memory");
    __builtin_amdgcn_s_barrier();
}

// --------------------------- weight transpose ------------------------------
// f,g: [512,64] fp32 -> fT,gT: [64,512] bf16.
__global__ __launch_bounds__(256) void wt_kernel(
    const float* __restrict__ f, const float* __restrict__ g,
    unsigned short* __restrict__ fT, unsigned short* __restrict__ gT)
{
    int gid = blockIdx.x * 256 + threadIdx.x;   // grid 64 -> 16384 threads
    for (int e = 0; e < 4; ++e) {
        int i = e * 16384 + gid;                // 0..65535
        int which = i >> 15;
        int j = i & 32767;
        int d = j >> 9, k = j & 511;
        const float* s = which ? g : f;
        unsigned short* dst = which ? gT : fT;
        dst[j] = f2bf(s[k * 64 + d]);           // dst[d][k] = src[k][d]
    }
}

// ----------------------------- V transpose ---------------------------------
// input_h [b][n][c] fp32 -> Vt [b][c][n] bf16.  64x64 tiles through LDS
// (stride 65 breaks bank conflicts on the column gathers).
__global__ __launch_bounds__(256) void vt_kernel(
    const float* __restrict__ ih, unsigned short* __restrict__ Vt)
{
    __shared__ unsigned short T[64 * 65];
    const int tid = threadIdx.x;
    const int bidx = blockIdx.x;
    const int bb = bidx >> 9;      // batch
    const int rem = bidx & 511;
    const int ct = rem >> 6;       // c tile 0..7
    const int nt = rem & 63;       // n tile 0..63

    for (int p = 0; p < 4; ++p) {
        int idx = p * 256 + tid;           // 0..1023
        int r = idx >> 4, gg = idx & 15;   // row 0..63, float4 group 0..15
        f4v v = *(const f4v*)(ih + ((size_t)bb * NPOS + nt * 64 + r) * CCH + ct * 64 + gg * 4);
        for (int j = 0; j < 4; ++j) T[r * 65 + gg * 4 + j] = f2bf(v[j]);
    }
    __syncthreads();
    for (int p = 0; p < 2; ++p) {
        int idx = p * 256 + tid;
        int c = idx >> 3, ng = idx & 7;
        unsigned short tmp[8];
        for (int j = 0; j < 8; ++j) tmp[j] = T[(ng * 8 + j) * 65 + c];
        *(s8v*)(Vt + ((size_t)bb * CCH + ct * 64 + c) * NPOS + nt * 64 + ng * 8) = *(const s8v*)tmp;
    }
}

// ------------------------------ projections --------------------------------
// which=0: Q = x @ g   (16384 rows, K=512, 64 cols).  which=1: K = ih @ f.
// R8: reg-staged tile prefetch + sync_lds (no vmcnt drain at barriers).
__global__ __launch_bounds__(256) void proj_kernel(
    const float* __restrict__ x,  const float* __restrict__ ih,
    const unsigned short* __restrict__ gT, const unsigned short* __restrict__ fT,
    unsigned short* __restrict__ Qg, unsigned short* __restrict__ Kf)
{
    __shared__ __align__(16) short Alds[128 * LSTR];
    __shared__ __align__(16) short Wlds[64 * LSTR];
    const int tid = threadIdx.x;
    const int wave = tid >> 6, lane = tid & 63;
    const int n15 = lane & 15, quad = lane >> 4;
    const int which = blockIdx.x >> 7;
    const int rb = (blockIdx.x & 127) * 128;
    const float* src = which ? ih : x;
    const unsigned short* wT  = which ? fT : gT;
    unsigned short* dst = which ? Kf : Qg;

    f4v acc[2][4];   // [row-tile][col-tile]
    for (int i = 0; i < 2; ++i)
        for (int j = 0; j < 4; ++j)
            acc[i][j] = f4v{0.f, 0.f, 0.f, 0.f};

    // per-thread tile coords (A: 8 chunks, W: 2 chunks)
    const int ar = tid >> 4, ag = tid & 15;   // +p*16 rows per chunk? no:
    // A chunk p covers rows (p*256+tid)>>4 -- keep original indexing below.
    f4v areg[8];
    s8v wreg[2];
    // prologue: load kc=0 tiles into registers
    for (int p = 0; p < 8; ++p) {
        int idx = p * 256 + tid;
        int r = idx >> 4, gg = idx & 15;
        areg[p] = *(const f4v*)(src + (size_t)(rb + r) * CCH + gg * 4);
    }
    for (int p = 0; p < 2; ++p) {
        int idx = p * 256 + tid;
        int c = idx >> 3, gg = idx & 7;
        wreg[p] = *(const s8v*)(wT + (size_t)c * CCH + gg * 8);
    }
    (void)ar; (void)ag;

    for (int kc = 0; kc < 8; ++kc) {
        // stage current tiles from registers (fp32 -> bf16 for A)
        for (int p = 0; p < 8; ++p) {
            int idx = p * 256 + tid;
            int r = idx >> 4, gg = idx & 15;
            s4v tv;
            for (int j = 0; j < 4; ++j) tv[j] = (short)f2bf(areg[p][j]);
            *(s4v*)&Alds[r * LSTR + gg * 4] = tv;
        }
        for (int p = 0; p < 2; ++p) {
            int idx = p * 256 + tid;
            int c = idx >> 3, gg = idx & 7;
            *(s8v*)&Wlds[c * LSTR + gg * 8] = wreg[p];
        }
        // prefetch kc+1 tiles into registers (stays in flight across barriers)
        if (kc < 7) {
            for (int p = 0; p < 8; ++p) {
                int idx = p * 256 + tid;
                int r = idx >> 4, gg = idx & 15;
                areg[p] = *(const f4v*)(src + (size_t)(rb + r) * CCH + (kc + 1) * 64 + gg * 4);
            }
            for (int p = 0; p < 2; ++p) {
                int idx = p * 256 + tid;
                int c = idx >> 3, gg = idx & 7;
                wreg[p] = *(const s8v*)(wT + (size_t)c * CCH + (kc + 1) * 64 + gg * 8);
            }
        }
        sync_lds();
        for (int kk = 0; kk < 2; ++kk) {       // two K=32 chunks of the 64-tile
            s8v af0 = *(const s8v*)&Alds[(wave * 32 +      n15) * LSTR + kk * 32 + quad * 8];
            s8v af1 = *(const s8v*)&Alds[(wave * 32 + 16 + n15) * LSTR + kk * 32 + quad * 8];
            for (int ct = 0; ct < 4; ++ct) {
                s8v bf = *(const s8v*)&Wlds[(ct * 16 + n15) * LSTR + kk * 32 + quad * 8];
                acc[0][ct] = __builtin_amdgcn_mfma_f32_16x16x32_bf16(af0, bf, acc[0][ct], 0, 0, 0);
                acc[1][ct] = __builtin_amdgcn_mfma_f32_16x16x32_bf16(af1, bf, acc[1][ct], 0, 0, 0);
            }
        }
        sync_lds();
    }
    for (int rt = 0; rt < 2; ++rt)
        for (int ct = 0; ct < 4; ++ct)
            for (int r = 0; r < 4; ++r) {
                int row = wave * 32 + rt * 16 + quad * 4 + r;
                int col = ct * 16 + n15;
                dst[(size_t)(rb + row) * DQK + col] = f2bf(acc[rt][ct][r]);
            }
}

// ------------------------------ flash attention ----------------------------
// One block per (batch, 64-row query tile), 1024 threads = 16 waves.
// Phase A: wave w computes S-tile (ti=w>>2, mi=w&3); denom in registers.
// Phase B: wave w owns 32-chan slice.  Single raw barrier per key-tile
// (K and P double-buffered); V prefetched one window ahead in registers.
__global__ __launch_bounds__(1024) void flash_kernel(
    const unsigned short* __restrict__ Qg,
    const unsigned short* __restrict__ Kf,
    const unsigned short* __restrict__ Vt,
    const float* __restrict__ xin,
    const float* __restrict__ gptr,
    float* __restrict__ out)
{
    __shared__ __align__(16) short Klds[2 * 64 * LSTR];  // double-buffered K
    __shared__ __align__(16) short Plds[2 * 64 * LSTR];  // double-buffered P
    __shared__ float l_part[4][64];                      // per-mi row partials
    __shared__ float l_s[64];

    const int tid = threadIdx.x;
    const int wave = tid >> 6;          // 0..15
    const int lane = tid & 63;
    const int n15 = lane & 15, quad = lane >> 4;
    const int bid = blockIdx.x;
    // XCD swizzle: batch b -> XCD pair so per-XCD Vt working set = 4MB.
    const int xcd = bid & 7;
    const int b = xcd >> 1;
    const int qt = (xcd & 1) + ((bid >> 3) << 1);
    const int qbase = qt * 64;

    const float SOFT_M = 20.0f;

    f4v acc[4][2];   // [query-tile(4x16)][channel-tile(2x16)]
    for (int i = 0; i < 4; ++i)
        for (int j = 0; j < 2; ++j)
            acc[i][j] = f4v{0.f, 0.f, 0.f, 0.f};
    f4v lsum = f4v{0.f, 0.f, 0.f, 0.f};   // denom partials, rows ti*16+quad*4+r

    // Phase-A tile assignment: wave w -> S rows ti*16.., key cols mi*16..
    const int ti = wave >> 2;
    const int mi = wave & 3;
    s8v qf[2];
    {
        const unsigned short* qp =
            Qg + ((size_t)b * NPOS + qbase + ti * 16 + n15) * DQK + quad * 8;
        qf[0] = *(const s8v*)(qp);
        qf[1] = *(const s8v*)(qp + 32);
    }

    const int cb = wave * 32;   // phase-B channel base for this wave
    const unsigned short* vp0 =
        Vt + ((size_t)b * CCH + cb + n15) * NPOS + quad * 8;
    const unsigned short* vp1 = vp0 + (size_t)16 * NPOS;

    // K staging: waves 0..7 stage (64 rows x 8 16B-groups = 512 threads)
    const int kr = tid >> 3, kg = tid & 7;           // valid for tid<512
    const unsigned short* kbase_p = Kf + ((size_t)b * NPOS + kr) * DQK + kg * 8;
    s8v kreg;
    if (tid < 512) {
        kreg = *(const s8v*)(kbase_p);
        *(s8v*)&Klds[kr * LSTR + kg * 8] = kreg;          // stage K(0)
        kreg = *(const s8v*)(kbase_p + (size_t)64 * DQK); // prefetch K(1)
    }
    // V(0) into current regs
    s8v vfc[2][2];
    vfc[0][0] = *(const s8v*)(vp0);
    vfc[0][1] = *(const s8v*)(vp0 + 32);
    vfc[1][0] = *(const s8v*)(vp1);
    vfc[1][1] = *(const s8v*)(vp1 + 32);
    sync_lds();

    for (int kb = 0; kb < NPOS / 64; ++kb) {
        const int m0 = kb * 64;
        // prefetch NEXT window's V into vfn (used next iteration; the raw
        // barrier does not drain these -- latency spans the whole window)
        const int mn = (kb + 1 < NPOS / 64) ? m0 + 64 : m0;
        s8v vfn[2][2];
        vfn[0][0] = *(const s8v*)(vp0 + mn);
        vfn[0][1] = *(const s8v*)(vp0 + mn + 32);
        vfn[1][0] = *(const s8v*)(vp1 + mn);
        vfn[1][1] = *(const s8v*)(vp1 + mn + 32);
        // stage K(kb+1) from kreg; prefetch K(kb+2)
        if (tid < 512 && kb + 1 < NPOS / 64) {
            *(s8v*)&Klds[((kb + 1) & 1) * 64 * LSTR + kr * LSTR + kg * 8] = kreg;
            if (kb + 2 < NPOS / 64)
                kreg = *(const s8v*)(kbase_p + (size_t)(m0 + 128) * DQK);
        }

        // ---- phase A: one 16x16 S tile per wave -> P -> Pbuf[kb&1];
        //      denominator partials accumulated in registers ----
        {
            const short* Kb = &Klds[(kb & 1) * 64 * LSTR];
            short* Pb = &Plds[(kb & 1) * 64 * LSTR];
            f4v s4 = f4v{0.f, 0.f, 0.f, 0.f};
            s8v kf0 = *(const s8v*)&Kb[(mi * 16 + n15) * LSTR + quad * 8];
            s8v kf1 = *(const s8v*)&Kb[(mi * 16 + n15) * LSTR + 32 + quad * 8];
            s4 = __builtin_amdgcn_mfma_f32_16x16x32_bf16(qf[0], kf0, s4, 0, 0, 0);
            s4 = __builtin_amdgcn_mfma_f32_16x16x32_bf16(qf[1], kf1, s4, 0, 0, 0);
            const int col = mi * 16 + n15;
            const int row0 = ti * 16 + quad * 4;
            for (int r = 0; r < 4; ++r) {
                unsigned short pb = f2bf(__expf(fminf(s4[r], 80.0f) - SOFT_M));
                Pb[(row0 + r) * LSTR + col] = (short)pb;
                lsum[r] += bf2f(pb);   // sum the ROUNDED value (matches P@1)
            }
        }
        sync_lds();   // lgkm drained (P visible, K reads done); vmcnt NOT drained

        // ---- phase B: O += P @ V for this wave's 32-chan slice ----
        {
            const short* Pb = &Plds[(kb & 1) * 64 * LSTR];
            for (int kk = 0; kk < 2; ++kk) {
                for (int q4 = 0; q4 < 4; ++q4) {
                    s8v af = *(const s8v*)&Pb[(q4 * 16 + n15) * LSTR + kk * 32 + quad * 8];
                    acc[q4][0] = __builtin_amdgcn_mfma_f32_16x16x32_bf16(
                        af, vfc[0][kk], acc[q4][0], 0, 0, 0);
                    acc[q4][1] = __builtin_amdgcn_mfma_f32_16x16x32_bf16(
                        af, vfc[1][kk], acc[q4][1], 0, 0, 0);
                }
            }
        }
        // rotate V prefetch
        vfc[0][0] = vfn[0][0]; vfc[0][1] = vfn[0][1];
        vfc[1][0] = vfn[1][0]; vfc[1][1] = vfn[1][1];
        // hazards: A(kb+1) writes Pbuf[(kb+1)&1]; stage(kb+1) writes
        // Klds[(kb+2)&1]; B(kb) reads Pbuf[kb&1] -- disjoint; all ds ops
        // before each raw barrier are lgkm-drained.
    }

    // ---- denominator: reduce lsum over the 16 n15 lanes (same quad = same
    //      rows), then combine the 4 mi-waves via LDS ----
    for (int d = 1; d < 16; d <<= 1)
        for (int r = 0; r < 4; ++r)
            lsum[r] += __shfl_xor(lsum[r], d);
    if (n15 == 0)
        for (int r = 0; r < 4; ++r)
            l_part[mi][ti * 16 + quad * 4 + r] = lsum[r];
    __syncthreads();
    if (tid < 64)
        l_s[tid] = l_part[0][tid] + l_part[1][tid] + l_part[2][tid] + l_part[3][tid];
    __syncthreads();

    // ---- epilogue: out = gamma * O / l + x  (fp32 I/O, scalar l reads) ----
    const float gamma = gptr[0];
    for (int q4 = 0; q4 < 4; ++q4) {
        for (int r = 0; r < 4; ++r) {
            const int row = q4 * 16 + quad * 4 + r;
            const float sc = gamma / l_s[row];
            const size_t base = ((size_t)b * NPOS + qbase + row) * CCH;
            const int col0 = cb + n15;
            const int col1 = cb + 16 + n15;
            out[base + col0] = acc[q4][0][r] * sc + xin[base + col0];
            out[base + col1] = acc[q4][1][r] * sc + xin[base + col1];
        }
    }
}

// ---------------------------------------------------------------------------
extern "C" void kernel_launch(void* const* d_in, const int* in_sizes, int n_in,
                              void* d_out, int out_size, void* d_ws, size_t ws_size,
                              hipStream_t stream)
{
    const float* x     = (const float*)d_in[0];
    const float* ih    = (const float*)d_in[1];
    const float* f     = (const float*)d_in[2];
    const float* g     = (const float*)d_in[3];
    const float* gamma = (const float*)d_in[4];
    float* out = (float*)d_out;

    char* ws = (char*)d_ws;
    unsigned short* fT = (unsigned short*)(ws + 0);         // 64x512 bf16 (64KB)
    unsigned short* gT = (unsigned short*)(ws + 65536);     // 64x512 bf16 (64KB)
    unsigned short* Qg = (unsigned short*)(ws + 131072);    // 16384x64 bf16 (2MB)
    unsigned short* Kf = (unsigned short*)(ws + 2228224);   // 16384x64 bf16 (2MB)
    unsigned short* Vt = (unsigned short*)(ws + 4325376);   // 4x512x4096 bf16 (16MB)
    // total ws use: 21,102,592 bytes (~20.1MB), non-overlapping.

    wt_kernel<<<64, 256, 0, stream>>>(f, g, fT, gT);
    vt_kernel<<<2048, 256, 0, stream>>>(ih, Vt);
    proj_kernel<<<256, 256, 0, stream>>>(x, ih, gT, fT, Qg, Kf);
    flash_kernel<<<256, 1024, 0, stream>>>(Qg, Kf, Vt, x, gamma, out);
}